// Round 4
// baseline (618.851 us; speedup 1.0000x reference)
//
#include <hip/hip_runtime.h>

// Problem constants
#define N_PTS   100000
#define P_CELLS 409600          // 640*640
#define NCLOUD  4               // B=2 batches x {prev, cur}; cloud c = b*2 + t

// Workspace layout (ws is large, we use ~13 MB):
//   [0)      k0[64],k1[64],k2[64],k3[64]  fused constants (1 KB)
//   [1024)   head[4*P] ints               (6.55 MB)
//   [+...]   node[4*N] float4             (6.4 MB)  {x,y,z,next-as-bits}
#define WS_HEAD_OFF 1024

// ---------------------------------------------------------------------------
// Kernel 0: fuse Linear+BN constants. 64 threads.
//   h_d = relu(x*k0[d] + y*k1[d] + z*k2[d] + k3[d])
// ---------------------------------------------------------------------------
__global__ void make_consts(
    const float* __restrict__ W,     const float* __restrict__ bvec,
    const float* __restrict__ gamma, const float* __restrict__ beta,
    const float* __restrict__ mean,  const float* __restrict__ var,
    float* __restrict__ k)
{
    int d = threadIdx.x;
    if (d >= 64) return;
    float s = gamma[d] * rsqrtf(var[d] + 1e-5f);
    k[d]       = W[d * 3 + 0] * s;
    k[64 + d]  = W[d * 3 + 1] * s;
    k[128 + d] = W[d * 3 + 2] * s;
    k[192 + d] = (bvec[d] - mean[d]) * s + beta[d];
}

// ---------------------------------------------------------------------------
// Kernel 1: build per-cell linked lists of masked points with fat nodes.
//   head[c*P + p] -> most recent gid, node[gid].w -> prev gid bits, -1 ends.
// ---------------------------------------------------------------------------
__global__ void build_lists(
    const float* __restrict__ prev_pcl, const int* __restrict__ prev_mask,
    const int*   __restrict__ prev_grid,
    const float* __restrict__ cur_pcl,  const int* __restrict__ cur_mask,
    const int*   __restrict__ cur_grid,
    int* __restrict__ head, float4* __restrict__ node)
{
    int gid = blockIdx.x * blockDim.x + threadIdx.x;
    if (gid >= NCLOUD * N_PTS) return;
    int c = gid / N_PTS;
    int n = gid - c * N_PTS;
    int t = c & 1;
    int b = c >> 1;
    const int*   msk = t ? cur_mask : prev_mask;
    const int*   grd = t ? cur_grid : prev_grid;
    const float* pcl = t ? cur_pcl  : prev_pcl;
    int e = b * N_PTS + n;
    if (!msk[e]) return;
    int p = grd[e];
    const float* q = pcl + (size_t)e * 3;
    int old = atomicExch(&head[c * P_CELLS + p], gid);
    node[gid] = make_float4(q[0], q[1], q[2], __int_as_float(old));
}

// ---------------------------------------------------------------------------
// Kernel 2: gather. One thread per (cloud c, cell p): chase chain (one 16 B
// load per hop), accumulate acc[64]. Epilogue: LDS transpose per 16-feature
// group so each wave store is global_store_dwordx4 covering 1 KB CONTIGUOUS
// in one feature plane (feature index wave-uniform) — long DRAM bursts
// instead of 64 interleaved 256 B streams. Output written exactly once.
// ---------------------------------------------------------------------------
#define LDS_STRIDE 260   // 260 words = 1040 B = 65*16 -> rows stay 16B-aligned
__global__ __launch_bounds__(256) void gather_kernel(
    const int* __restrict__ head, const float4* __restrict__ node,
    const float* __restrict__ k,   // k0|k1|k2|k3, 64 each
    float* __restrict__ out)
{
    __shared__ float lds[16 * LDS_STRIDE];

    const int tid  = threadIdx.x;
    const int lane = tid & 63;
    const int wv   = tid >> 6;                          // wave id 0..3
    const int c    = blockIdx.y;                        // cloud 0..3
    const int cell0 = blockIdx.x * 256;                 // block's first cell
    const int p    = cell0 + tid;

    float acc[64];
#pragma unroll
    for (int d = 0; d < 64; ++d) acc[d] = 0.f;

    int idx = head[c * P_CELLS + p];                    // coalesced

    while (__ballot(idx >= 0)) {
        const bool act = (idx >= 0);
        float4 nd = node[act ? idx : 0];                // predicated fat node
        const float m = act ? 1.f : 0.f;
        const float x = nd.x, y = nd.y, z = nd.z;
        if (act) idx = __float_as_int(nd.w);
#pragma unroll
        for (int d = 0; d < 64; ++d) {
            float v = fmaf(x, k[d], fmaf(y, k[64 + d], fmaf(z, k[128 + d], k[192 + d])));
            acc[d] = fmaf(fmaxf(v, 0.f), m, acc[d]);    // fmax kills any NaN*0
        }
    }

    // Epilogue: 4 groups of 16 features through LDS.
    float* obase = out + (size_t)c * 64u * P_CELLS + cell0;
#pragma unroll 1
    for (int g = 0; g < 4; ++g) {
        __syncthreads();                                // reads(g-1) done
#pragma unroll
        for (int f = 0; f < 16; ++f)
            lds[f * LDS_STRIDE + tid] = acc[g * 16 + f];   // 2-way bank alias: free
        __syncthreads();
#pragma unroll
        for (int r = 0; r < 4; ++r) {
            const int f = r * 4 + wv;                   // wave-uniform feature
            float4 v = *(const float4*)&lds[f * LDS_STRIDE + lane * 4];
            *(float4*)(obase + (size_t)(g * 16 + f) * P_CELLS + lane * 4) = v;
        }
    }
}

// ---------------------------------------------------------------------------
extern "C" void kernel_launch(void* const* d_in, const int* in_sizes, int n_in,
                              void* d_out, int out_size, void* d_ws, size_t ws_size,
                              hipStream_t stream) {
    const float* prev_pcl  = (const float*)d_in[0];
    const int*   prev_mask = (const int*)  d_in[1];
    const int*   prev_grid = (const int*)  d_in[2];
    const float* cur_pcl   = (const float*)d_in[3];
    const int*   cur_mask  = (const int*)  d_in[4];
    const int*   cur_grid  = (const int*)  d_in[5];
    const float* W     = (const float*)d_in[6];
    const float* bvec  = (const float*)d_in[7];
    const float* gam   = (const float*)d_in[8];
    const float* bet   = (const float*)d_in[9];
    const float* mean  = (const float*)d_in[10];
    const float* var   = (const float*)d_in[11];
    float* out = (float*)d_out;

    float*  consts = (float*)d_ws;
    int*    head   = (int*)((char*)d_ws + WS_HEAD_OFF);
    float4* node   = (float4*)((char*)d_ws + WS_HEAD_OFF
                               + (size_t)NCLOUD * P_CELLS * sizeof(int));

    make_consts<<<1, 64, 0, stream>>>(W, bvec, gam, bet, mean, var, consts);
    hipMemsetAsync(head, 0xFF, (size_t)NCLOUD * P_CELLS * sizeof(int), stream);

    build_lists<<<(NCLOUD * N_PTS + 255) / 256, 256, 0, stream>>>(
        prev_pcl, prev_mask, prev_grid, cur_pcl, cur_mask, cur_grid,
        head, node);

    dim3 ggrid(P_CELLS / 256, NCLOUD);
    gather_kernel<<<ggrid, 256, 0, stream>>>(head, node, consts, out);
}

// Round 5
// 458.956 us; speedup vs baseline: 1.3484x; 1.3484x over previous
//
#include <hip/hip_runtime.h>

// Problem constants
#define N_PTS   100000
#define P_CELLS 409600          // 640*640
#define NCLOUD  4               // B=2 batches x {prev, cur}; cloud c = b*2 + t

// Workspace layout (ws is large, we use ~13 MB):
//   [0)      k0[64],k1[64],k2[64],k3[64]  fused constants (1 KB)
//   [1024)   head[4*P] ints               (6.55 MB)
//   [+...]   node[4*N] float4             (6.4 MB)  {x,y,z,next-as-bits}
#define WS_HEAD_OFF 1024

// ---------------------------------------------------------------------------
// Kernel 0: fuse Linear+BN constants. 64 threads.
//   h_d = relu(x*k0[d] + y*k1[d] + z*k2[d] + k3[d])
// ---------------------------------------------------------------------------
__global__ void make_consts(
    const float* __restrict__ W,     const float* __restrict__ bvec,
    const float* __restrict__ gamma, const float* __restrict__ beta,
    const float* __restrict__ mean,  const float* __restrict__ var,
    float* __restrict__ k)
{
    int d = threadIdx.x;
    if (d >= 64) return;
    float s = gamma[d] * rsqrtf(var[d] + 1e-5f);
    k[d]       = W[d * 3 + 0] * s;
    k[64 + d]  = W[d * 3 + 1] * s;
    k[128 + d] = W[d * 3 + 2] * s;
    k[192 + d] = (bvec[d] - mean[d]) * s + beta[d];
}

// ---------------------------------------------------------------------------
// Kernel 1: build per-cell linked lists of masked points with fat nodes.
//   head[c*P + p] -> most recent gid, node[gid].w -> prev gid bits, -1 ends.
// ---------------------------------------------------------------------------
__global__ void build_lists(
    const float* __restrict__ prev_pcl, const int* __restrict__ prev_mask,
    const int*   __restrict__ prev_grid,
    const float* __restrict__ cur_pcl,  const int* __restrict__ cur_mask,
    const int*   __restrict__ cur_grid,
    int* __restrict__ head, float4* __restrict__ node)
{
    int gid = blockIdx.x * blockDim.x + threadIdx.x;
    if (gid >= NCLOUD * N_PTS) return;
    int c = gid / N_PTS;
    int n = gid - c * N_PTS;
    int t = c & 1;
    int b = c >> 1;
    const int*   msk = t ? cur_mask : prev_mask;
    const int*   grd = t ? cur_grid : prev_grid;
    const float* pcl = t ? cur_pcl  : prev_pcl;
    int e = b * N_PTS + n;
    if (!msk[e]) return;
    int p = grd[e];
    const float* q = pcl + (size_t)e * 3;
    int old = atomicExch(&head[c * P_CELLS + p], gid);
    node[gid] = make_float4(q[0], q[1], q[2], __int_as_float(old));
}

// ---------------------------------------------------------------------------
// Kernel 2: gather. One thread per (cloud c, cell p): chase chain (one 16 B
// load per hop), accumulate acc[64] in VGPRs. Epilogue: LDS transpose per
// 16-feature group so each wave store is global_store_dwordx4 covering 1 KB
// CONTIGUOUS in one feature plane. The group loop is FULLY UNROLLED so every
// acc[] index is a compile-time constant — runtime indexing (R4's
// `#pragma unroll 1`) demoted acc to scratch and cost +160 us of hidden
// HBM spill traffic. Output written exactly once.
// ---------------------------------------------------------------------------
#define LDS_STRIDE 260   // 260 words = 1040 B = 65*16 -> rows stay 16B-aligned
__global__ __launch_bounds__(256) void gather_kernel(
    const int* __restrict__ head, const float4* __restrict__ node,
    const float* __restrict__ k,   // k0|k1|k2|k3, 64 each
    float* __restrict__ out)
{
    __shared__ float lds[16 * LDS_STRIDE];

    const int tid  = threadIdx.x;
    const int lane = tid & 63;
    const int wv   = tid >> 6;                          // wave id 0..3
    const int c    = blockIdx.y;                        // cloud 0..3
    const int cell0 = blockIdx.x * 256;                 // block's first cell
    const int p    = cell0 + tid;

    float acc[64];
#pragma unroll
    for (int d = 0; d < 64; ++d) acc[d] = 0.f;

    int idx = head[c * P_CELLS + p];                    // coalesced

    while (__ballot(idx >= 0)) {
        const bool act = (idx >= 0);
        float4 nd = node[act ? idx : 0];                // predicated fat node
        const float m = act ? 1.f : 0.f;
        const float x = nd.x, y = nd.y, z = nd.z;
        if (act) idx = __float_as_int(nd.w);
#pragma unroll
        for (int d = 0; d < 64; ++d) {
            float v = fmaf(x, k[d], fmaf(y, k[64 + d], fmaf(z, k[128 + d], k[192 + d])));
            acc[d] = fmaf(fmaxf(v, 0.f), m, acc[d]);    // fmax kills any NaN*0
        }
    }

    // Epilogue: 4 groups of 16 features through LDS. FULL unroll: all acc[]
    // indices static -> acc stays in VGPRs.
    float* obase = out + (size_t)c * 64u * P_CELLS + cell0;
#pragma unroll
    for (int g = 0; g < 4; ++g) {
        __syncthreads();                                // reads(g-1) done
#pragma unroll
        for (int f = 0; f < 16; ++f)
            lds[f * LDS_STRIDE + tid] = acc[g * 16 + f];   // g,f both static
        __syncthreads();
#pragma unroll
        for (int r = 0; r < 4; ++r) {
            const int f = r * 4 + wv;                   // wave-uniform feature
            float4 v = *(const float4*)&lds[f * LDS_STRIDE + lane * 4];
            *(float4*)(obase + (size_t)(g * 16 + f) * P_CELLS + lane * 4) = v;
        }
    }
}

// ---------------------------------------------------------------------------
extern "C" void kernel_launch(void* const* d_in, const int* in_sizes, int n_in,
                              void* d_out, int out_size, void* d_ws, size_t ws_size,
                              hipStream_t stream) {
    const float* prev_pcl  = (const float*)d_in[0];
    const int*   prev_mask = (const int*)  d_in[1];
    const int*   prev_grid = (const int*)  d_in[2];
    const float* cur_pcl   = (const float*)d_in[3];
    const int*   cur_mask  = (const int*)  d_in[4];
    const int*   cur_grid  = (const int*)  d_in[5];
    const float* W     = (const float*)d_in[6];
    const float* bvec  = (const float*)d_in[7];
    const float* gam   = (const float*)d_in[8];
    const float* bet   = (const float*)d_in[9];
    const float* mean  = (const float*)d_in[10];
    const float* var   = (const float*)d_in[11];
    float* out = (float*)d_out;

    float*  consts = (float*)d_ws;
    int*    head   = (int*)((char*)d_ws + WS_HEAD_OFF);
    float4* node   = (float4*)((char*)d_ws + WS_HEAD_OFF
                               + (size_t)NCLOUD * P_CELLS * sizeof(int));

    make_consts<<<1, 64, 0, stream>>>(W, bvec, gam, bet, mean, var, consts);
    hipMemsetAsync(head, 0xFF, (size_t)NCLOUD * P_CELLS * sizeof(int), stream);

    build_lists<<<(NCLOUD * N_PTS + 255) / 256, 256, 0, stream>>>(
        prev_pcl, prev_mask, prev_grid, cur_pcl, cur_mask, cur_grid,
        head, node);

    dim3 ggrid(P_CELLS / 256, NCLOUD);
    gather_kernel<<<ggrid, 256, 0, stream>>>(head, node, consts, out);
}